// Round 2
// baseline (2579.424 us; speedup 1.0000x reference)
//
#include <hip/hip_runtime.h>
#include <hip/hip_fp16.h>

#define AS1 __attribute__((address_space(1)))
#define AS3 __attribute__((address_space(3)))

typedef __bf16 bf16x8 __attribute__((ext_vector_type(8)));
typedef float f32x4 __attribute__((ext_vector_type(4)));

constexpr int NROWS = 16384;
constexpr int DIM   = 1024;
constexpr int KCENT = 12288;
constexpr int NCLS  = 4096;
constexpr int BM = 128, BN = 128, BK = 32;
constexpr int KSTEPS = DIM / BK;      // 32
constexpr int STATS_T = KCENT / 64;   // 192 stat tiles (64 cols each)

// ---------- kernel 0: fp32 -> (hi, lo) bf16 split (Ootomo decomposition) ----------
__global__ void split_convert(const float4* __restrict__ src,
                              ushort4* __restrict__ hi, ushort4* __restrict__ lo, int n4) {
  int i = blockIdx.x * blockDim.x + threadIdx.x;
  if (i >= n4) return;
  float4 v = src[i];
  float a[4] = {v.x, v.y, v.z, v.w};
  unsigned short hs[4], ls[4];
#pragma unroll
  for (int j = 0; j < 4; ++j) {
    unsigned u = __builtin_bit_cast(unsigned, a[j]);
    unsigned r = (u + 0x7fffu + ((u >> 16) & 1u)) & 0xffff0000u;  // RNE to bf16
    hs[j] = (unsigned short)(r >> 16);
    float hf = __builtin_bit_cast(float, r);
    float res = a[j] - hf;
    unsigned u2 = __builtin_bit_cast(unsigned, res);
    unsigned r2 = (u2 + 0x7fffu + ((u2 >> 16) & 1u)) >> 16;
    ls[j] = (unsigned short)r2;
  }
  hi[i] = make_ushort4(hs[0], hs[1], hs[2], hs[3]);
  lo[i] = make_ushort4(ls[0], ls[1], ls[2], ls[3]);
}

// ---------- kernel 0b: labels int32 -> ushort ----------
__global__ void labels_to_u16(const int* __restrict__ lab, ushort* __restrict__ lab16, int n) {
  int i = blockIdx.x * blockDim.x + threadIdx.x;
  if (i < n) lab16[i] = (ushort)lab[i];
}

// ---------- kernel 1: split-bf16 GEMM + per-tile softmax stats epilogue ----------
// sim[r][c] = X[r]·C[c]; stores exp(sim - m_tile) as fp16, (m_tile, sumexp_tile) per (row, 64-col tile)
__launch_bounds__(256, 2)
__global__ void gemm_softmax(const __bf16* __restrict__ Xh, const __bf16* __restrict__ Xl,
                             const __bf16* __restrict__ Ch, const __bf16* __restrict__ Cl,
                             _Float16* __restrict__ expo, float2* __restrict__ stats,
                             int row0) {
  __shared__ __bf16 sAh[BM * BK], sAl[BM * BK], sBh[BM * BK], sBl[BM * BK];
  const int tid  = threadIdx.x;
  const int lane = tid & 63;
  const int wv   = tid >> 6;
  const int wr   = wv >> 1, wc = wv & 1;   // 2x2 wave grid, each wave owns 64x64
  const int bm = blockIdx.x, bn = blockIdx.y;
  const size_t arow0 = (size_t)row0 + (size_t)bm * BM;  // global X row base
  const size_t brow0 = (size_t)bn * BN;                 // centroid row base
  const int lbase = bm * BM;                            // chunk-local row base

  f32x4 acc[4][4] = {};

  // staging: issue iss in [0,8) covers LDS bytes iss*1024..+1024 of a [128][32] bf16 tile
  const int srow = lane >> 2;            // + iss*16
  const int scol = (lane & 3) * 8;       // elements within row

  for (int ks = 0; ks < KSTEPS; ++ks) {
    __syncthreads();  // previous iteration's ds_reads done before overwrite
    const int kcol = ks * BK;
#pragma unroll
    for (int s = 0; s < 2; ++s) {
      const int iss = wv * 2 + s;
      const int r = iss * 16 + srow;
      const size_t ga = (arow0 + (size_t)r) * DIM + kcol + scol;
      const size_t gb = (brow0 + (size_t)r) * DIM + kcol + scol;
      const int lo_off = iss * 512;  // elements
      __builtin_amdgcn_global_load_lds((const AS1 void*)(Xh + ga), (AS3 void*)(sAh + lo_off), 16, 0, 0);
      __builtin_amdgcn_global_load_lds((const AS1 void*)(Xl + ga), (AS3 void*)(sAl + lo_off), 16, 0, 0);
      __builtin_amdgcn_global_load_lds((const AS1 void*)(Ch + gb), (AS3 void*)(sBh + lo_off), 16, 0, 0);
      __builtin_amdgcn_global_load_lds((const AS1 void*)(Cl + gb), (AS3 void*)(sBl + lo_off), 16, 0, 0);
    }
    __syncthreads();  // staging complete

    bf16x8 ah[4], al[4], bh[4], bl[4];
    const int kk = (lane >> 4) * 8;
    const int rsel = lane & 15;
#pragma unroll
    for (int m = 0; m < 4; ++m) {
      const int ar = wr * 64 + m * 16 + rsel;
      ah[m] = *(const bf16x8*)(sAh + ar * BK + kk);
      al[m] = *(const bf16x8*)(sAl + ar * BK + kk);
      const int br = wc * 64 + m * 16 + rsel;
      bh[m] = *(const bf16x8*)(sBh + br * BK + kk);
      bl[m] = *(const bf16x8*)(sBl + br * BK + kk);
    }
#pragma unroll
    for (int m = 0; m < 4; ++m)
#pragma unroll
      for (int n = 0; n < 4; ++n) {
        acc[m][n] = __builtin_amdgcn_mfma_f32_16x16x32_bf16(ah[m], bh[n], acc[m][n], 0, 0, 0);
        acc[m][n] = __builtin_amdgcn_mfma_f32_16x16x32_bf16(ah[m], bl[n], acc[m][n], 0, 0, 0);
        acc[m][n] = __builtin_amdgcn_mfma_f32_16x16x32_bf16(al[m], bh[n], acc[m][n], 0, 0, 0);
      }
  }

  // epilogue: C/D layout col = lane&15, row = (lane>>4)*4 + reg  [m89-verified]
  const int g  = lane >> 4;
  const int cl = lane & 15;
  const int tileIdx = bn * 2 + wc;
#pragma unroll
  for (int m = 0; m < 4; ++m) {
#pragma unroll
    for (int j = 0; j < 4; ++j) {
      const int lrow = lbase + wr * 64 + m * 16 + g * 4 + j;  // chunk-local row
      float v0 = acc[m][0][j], v1 = acc[m][1][j], v2 = acc[m][2][j], v3 = acc[m][3][j];
      float mx = fmaxf(fmaxf(v0, v1), fmaxf(v2, v3));
#pragma unroll
      for (int s2 = 1; s2 < 16; s2 <<= 1) mx = fmaxf(mx, __shfl_xor(mx, s2, 64));
      float p0 = __expf(v0 - mx), p1 = __expf(v1 - mx), p2 = __expf(v2 - mx), p3 = __expf(v3 - mx);
      float sm = p0 + p1 + p2 + p3;
#pragma unroll
      for (int s2 = 1; s2 < 16; s2 <<= 1) sm += __shfl_xor(sm, s2, 64);
      _Float16* ep = expo + (size_t)lrow * KCENT + brow0 + wc * 64;
      ep[ 0 + cl] = (_Float16)p0;
      ep[16 + cl] = (_Float16)p1;
      ep[32 + cl] = (_Float16)p2;
      ep[48 + cl] = (_Float16)p3;
      if (cl == 0) stats[(size_t)lrow * STATS_T + tileIdx] = make_float2(mx, sm);
    }
  }
}

// ---------- kernel 2: per-row combine + scatter into 4096 class bins ----------
// One row per block. Vectorized 16B loads, all loads issued before the atomic loop (MLP).
__launch_bounds__(256)
__global__ void scatter_classes(const _Float16* __restrict__ expo, const float2* __restrict__ stats,
                                const ushort* __restrict__ lab16, float* __restrict__ out, int row0) {
  __shared__ __align__(16) float bins[NCLS];   // 16 KB
  __shared__ float cf[STATS_T];                // 768 B
  __shared__ float red[8];
  const int row = blockIdx.x;
  const int tid = threadIdx.x;
  const int lane = tid & 63;
  const int wv = tid >> 6;

  for (int i = tid; i < NCLS; i += 256) bins[i] = 0.f;

  // --- combine per-tile stats: m = max(mt), Z = sum(zt * exp(mt - m)) ---
  float mt = -3.4e38f, zt = 0.f;
  if (tid < STATS_T) {
    float2 s = stats[(size_t)row * STATS_T + tid];
    mt = s.x; zt = s.y;
  }
  float m = mt;
#pragma unroll
  for (int s2 = 1; s2 < 64; s2 <<= 1) m = fmaxf(m, __shfl_xor(m, s2, 64));
  if (lane == 0) red[wv] = m;
  __syncthreads();
  m = fmaxf(fmaxf(red[0], red[1]), fmaxf(red[2], red[3]));
  float e = (tid < STATS_T) ? __expf(mt - m) : 0.f;
  float z = zt * e;
#pragma unroll
  for (int s2 = 1; s2 < 64; s2 <<= 1) z += __shfl_xor(z, s2, 64);
  if (lane == 0) red[4 + wv] = z;
  __syncthreads();
  z = (red[4] + red[5]) + (red[6] + red[7]);
  if (tid < STATS_T) cf[tid] = e / z;
  __syncthreads();

  // --- main scatter: 8 fp16 + 8 labels per thread per iter, 6 iters, loads hoisted ---
  const uint4* ep8 = (const uint4*)(expo + (size_t)row * KCENT);   // 8 fp16 per uint4
  const uint4* lb8 = (const uint4*)lab16;                          // 8 labels per uint4
  uint4 ev[6], lv[6];
#pragma unroll
  for (int i = 0; i < 6; ++i) ev[i] = ep8[i * 256 + tid];
#pragma unroll
  for (int i = 0; i < 6; ++i) lv[i] = lb8[i * 256 + tid];
#pragma unroll
  for (int i = 0; i < 6; ++i) {
    const int v = i * 256 + tid;
    const float c = cf[v >> 3];
    const uint4 ee = ev[i], ll = lv[i];
    unsigned ws[4] = {ee.x, ee.y, ee.z, ee.w};
    unsigned ls[4] = {ll.x, ll.y, ll.z, ll.w};
#pragma unroll
    for (int j = 0; j < 4; ++j) {
      float plo = (float)__builtin_bit_cast(_Float16, (unsigned short)(ws[j] & 0xffffu));
      float phi = (float)__builtin_bit_cast(_Float16, (unsigned short)(ws[j] >> 16));
      atomicAdd(&bins[ls[j] & 0xffffu], plo * c);
      atomicAdd(&bins[ls[j] >> 16],     phi * c);
    }
  }
  __syncthreads();

  float4* orow = (float4*)(out + (size_t)(row0 + row) * NCLS);
  const float4* b4 = (const float4*)bins;
  for (int i = tid; i < NCLS / 4; i += 256) orow[i] = b4[i];
}

extern "C" void kernel_launch(void* const* d_in, const int* in_sizes, int n_in,
                              void* d_out, int out_size, void* d_ws, size_t ws_size,
                              hipStream_t stream) {
  (void)in_sizes; (void)n_in; (void)out_size;
  const float* X = (const float*)d_in[0];
  const float* C = (const float*)d_in[1];
  const int* labels = (const int*)d_in[2];
  float* out = (float*)d_out;

  char* ws = (char*)d_ws;
  size_t off = 0;
  auto carve = [&](size_t bytes) -> char* {
    char* p = ws + off;
    off += (bytes + 255) & ~(size_t)255;
    return p;
  };
  __bf16* Xh = (__bf16*)carve((size_t)NROWS * DIM * 2);
  __bf16* Xl = (__bf16*)carve((size_t)NROWS * DIM * 2);
  __bf16* Ch = (__bf16*)carve((size_t)KCENT * DIM * 2);
  __bf16* Cl = (__bf16*)carve((size_t)KCENT * DIM * 2);
  ushort* lab16 = (ushort*)carve((size_t)KCENT * 2);
  const size_t fixed = off;

  // chunk rows so per-chunk scratch (fp16 exp + stats) fits ws
  const size_t per_row = (size_t)KCENT * 2 + (size_t)STATS_T * 8;
  size_t avail = (ws_size > fixed + 4096) ? (ws_size - fixed - 4096) : 0;
  long Rmax = (long)(avail / per_row);
  Rmax = (Rmax / 128) * 128;
  if (Rmax < 128) Rmax = 128;
  if (Rmax > NROWS) Rmax = NROWS;
  _Float16* expo = (_Float16*)carve((size_t)Rmax * KCENT * 2);
  float2* stats  = (float2*)carve((size_t)Rmax * STATS_T * 8);

  {
    int n4x = NROWS * DIM / 4;
    split_convert<<<(n4x + 255) / 256, 256, 0, stream>>>((const float4*)X, (ushort4*)Xh, (ushort4*)Xl, n4x);
    int n4c = KCENT * DIM / 4;
    split_convert<<<(n4c + 255) / 256, 256, 0, stream>>>((const float4*)C, (ushort4*)Ch, (ushort4*)Cl, n4c);
    labels_to_u16<<<(KCENT + 255) / 256, 256, 0, stream>>>(labels, lab16, KCENT);
  }

  for (int r0 = 0; r0 < NROWS; r0 += (int)Rmax) {
    int R = (NROWS - r0 < (int)Rmax) ? (NROWS - r0) : (int)Rmax;
    dim3 grid(R / BM, KCENT / BN);
    gemm_softmax<<<grid, 256, 0, stream>>>(Xh, Xl, Ch, Cl, expo, stats, r0);
    scatter_classes<<<R, 256, 0, stream>>>(expo, stats, lab16, out, r0);
  }
}

// Round 4
// 1725.002 us; speedup vs baseline: 1.4953x; 1.4953x over previous
//
#include <hip/hip_runtime.h>
#include <hip/hip_fp16.h>

#define AS1 __attribute__((address_space(1)))
#define AS3 __attribute__((address_space(3)))

typedef __bf16 bf16x8 __attribute__((ext_vector_type(8)));
typedef float f32x4 __attribute__((ext_vector_type(4)));

constexpr int NROWS = 16384;
constexpr int DIM   = 1024;
constexpr int KCENT = 12288;
constexpr int NCLS  = 4096;
constexpr int BM = 128, BN = 128, BK = 32;
constexpr int KSTEPS = DIM / BK;      // 32
constexpr int STATS_T = KCENT / 64;   // 192 stat tiles (64 cols each)

__device__ __forceinline__ unsigned short f2bf_rne(float x) {
  unsigned u = __builtin_bit_cast(unsigned, x);
  return (unsigned short)((u + 0x7fffu + ((u >> 16) & 1u)) >> 16);
}

// ---------- kernel P: build label-sorted permutation (single block, deterministic) ----------
// iperm[p] = original centroid index at sorted position p; segstart[c] = first position of class c.
__launch_bounds__(256)
__global__ void build_perm(const int* __restrict__ lab, int* __restrict__ iperm,
                           ushort* __restrict__ segstart) {
  __shared__ ushort slab[KCENT];        // 24 KB
  __shared__ unsigned scnt[NCLS];       // 16 KB (counts, then cursors)
  __shared__ unsigned sstart[NCLS + 1]; // 16 KB
  __shared__ unsigned redw[4];
  const int tid = threadIdx.x;
  const int lane = tid & 63, wv = tid >> 6;

  for (int i = tid; i < KCENT; i += 256) slab[i] = (ushort)lab[i];
  for (int i = tid; i < NCLS; i += 256) scnt[i] = 0u;
  __syncthreads();
  for (int i = tid; i < KCENT; i += 256) atomicAdd(&scnt[slab[i]], 1u);
  __syncthreads();

  // exclusive scan over 4096 counts: 16 per thread
  unsigned loc = 0;
#pragma unroll
  for (int j = 0; j < 16; ++j) loc += scnt[tid * 16 + j];
  unsigned sc = loc;
#pragma unroll
  for (int off = 1; off < 64; off <<= 1) {
    unsigned v = __shfl_up(sc, off, 64);
    if (lane >= off) sc += v;
  }
  if (lane == 63) redw[wv] = sc;
  __syncthreads();
  unsigned wbase = 0;
  for (int w = 0; w < wv; ++w) wbase += redw[w];
  unsigned run = wbase + sc - loc;  // exclusive prefix of this thread's chunk
#pragma unroll
  for (int j = 0; j < 16; ++j) {
    sstart[tid * 16 + j] = run;
    run += scnt[tid * 16 + j];
  }
  if (tid == 255) sstart[NCLS] = run;  // == KCENT
  __syncthreads();

  // cursors = starts, then place (order nondeterministic; fixed by the sort below)
  for (int i = tid; i < NCLS; i += 256) scnt[i] = sstart[i];
  __syncthreads();
  for (int i = tid; i < KCENT; i += 256) {
    unsigned pos = atomicAdd(&scnt[slab[i]], 1u);
    iperm[pos] = i;
  }
  __syncthreads();
  // deterministic within-class order: ascending original index (segments are tiny, avg 3)
  for (int c = tid; c < NCLS; c += 256) {
    int a = (int)sstart[c], b = (int)sstart[c + 1];
    for (int i = a + 1; i < b; ++i) {
      int v = iperm[i], j = i - 1;
      while (j >= a && iperm[j] > v) { iperm[j + 1] = iperm[j]; --j; }
      iperm[j + 1] = v;
    }
  }
  for (int i = tid; i <= NCLS; i += 256) segstart[i] = (ushort)sstart[i];
}

// ---------- kernel 0a: fp32 -> (hi, lo) bf16 split (Ootomo), identity order (for X) ----------
__global__ void split_convert(const float4* __restrict__ src,
                              ushort4* __restrict__ hi, ushort4* __restrict__ lo, int n4) {
  int i = blockIdx.x * blockDim.x + threadIdx.x;
  if (i >= n4) return;
  float4 v = src[i];
  float a[4] = {v.x, v.y, v.z, v.w};
  unsigned short hs[4], ls[4];
#pragma unroll
  for (int j = 0; j < 4; ++j) {
    unsigned u = __builtin_bit_cast(unsigned, a[j]);
    unsigned r = (u + 0x7fffu + ((u >> 16) & 1u)) & 0xffff0000u;
    hs[j] = (unsigned short)(r >> 16);
    float hf = __builtin_bit_cast(float, r);
    ls[j] = f2bf_rne(a[j] - hf);
  }
  hi[i] = make_ushort4(hs[0], hs[1], hs[2], hs[3]);
  lo[i] = make_ushort4(ls[0], ls[1], ls[2], ls[3]);
}

// ---------- kernel 0b: split + row permutation (for centroids): dst row p = src row iperm[p] ----------
__launch_bounds__(256)
__global__ void split_convert_perm(const float4* __restrict__ src, const int* __restrict__ iperm,
                                   ushort4* __restrict__ hi, ushort4* __restrict__ lo) {
  const int p = blockIdx.x;               // permuted (dst) row
  const int srow = iperm[p];
  const int t = threadIdx.x;              // 256 threads x float4 = 1024 floats
  float4 v = src[(size_t)srow * (DIM / 4) + t];
  float a[4] = {v.x, v.y, v.z, v.w};
  unsigned short hs[4], ls[4];
#pragma unroll
  for (int j = 0; j < 4; ++j) {
    unsigned u = __builtin_bit_cast(unsigned, a[j]);
    unsigned r = (u + 0x7fffu + ((u >> 16) & 1u)) & 0xffff0000u;
    hs[j] = (unsigned short)(r >> 16);
    float hf = __builtin_bit_cast(float, r);
    ls[j] = f2bf_rne(a[j] - hf);
  }
  hi[(size_t)p * (DIM / 4) + t] = make_ushort4(hs[0], hs[1], hs[2], hs[3]);
  lo[(size_t)p * (DIM / 4) + t] = make_ushort4(ls[0], ls[1], ls[2], ls[3]);
}

// ---------- kernel 1: split-bf16 GEMM + per-tile softmax stats epilogue (unchanged) ----------
__launch_bounds__(256, 2)
__global__ void gemm_softmax(const __bf16* __restrict__ Xh, const __bf16* __restrict__ Xl,
                             const __bf16* __restrict__ Ch, const __bf16* __restrict__ Cl,
                             _Float16* __restrict__ expo, float2* __restrict__ stats,
                             int row0) {
  __shared__ __bf16 sAh[BM * BK], sAl[BM * BK], sBh[BM * BK], sBl[BM * BK];
  const int tid  = threadIdx.x;
  const int lane = tid & 63;
  const int wv   = tid >> 6;
  const int wr   = wv >> 1, wc = wv & 1;   // 2x2 wave grid, each wave owns 64x64
  const int bm = blockIdx.x, bn = blockIdx.y;
  const size_t arow0 = (size_t)row0 + (size_t)bm * BM;
  const size_t brow0 = (size_t)bn * BN;
  const int lbase = bm * BM;

  f32x4 acc[4][4] = {};

  const int srow = lane >> 2;
  const int scol = (lane & 3) * 8;

  for (int ks = 0; ks < KSTEPS; ++ks) {
    __syncthreads();
    const int kcol = ks * BK;
#pragma unroll
    for (int s = 0; s < 2; ++s) {
      const int iss = wv * 2 + s;
      const int r = iss * 16 + srow;
      const size_t ga = (arow0 + (size_t)r) * DIM + kcol + scol;
      const size_t gb = (brow0 + (size_t)r) * DIM + kcol + scol;
      const int lo_off = iss * 512;
      __builtin_amdgcn_global_load_lds((const AS1 void*)(Xh + ga), (AS3 void*)(sAh + lo_off), 16, 0, 0);
      __builtin_amdgcn_global_load_lds((const AS1 void*)(Xl + ga), (AS3 void*)(sAl + lo_off), 16, 0, 0);
      __builtin_amdgcn_global_load_lds((const AS1 void*)(Ch + gb), (AS3 void*)(sBh + lo_off), 16, 0, 0);
      __builtin_amdgcn_global_load_lds((const AS1 void*)(Cl + gb), (AS3 void*)(sBl + lo_off), 16, 0, 0);
    }
    __syncthreads();

    bf16x8 ah[4], al[4], bh[4], bl[4];
    const int kk = (lane >> 4) * 8;
    const int rsel = lane & 15;
#pragma unroll
    for (int m = 0; m < 4; ++m) {
      const int ar = wr * 64 + m * 16 + rsel;
      ah[m] = *(const bf16x8*)(sAh + ar * BK + kk);
      al[m] = *(const bf16x8*)(sAl + ar * BK + kk);
      const int br = wc * 64 + m * 16 + rsel;
      bh[m] = *(const bf16x8*)(sBh + br * BK + kk);
      bl[m] = *(const bf16x8*)(sBl + br * BK + kk);
    }
#pragma unroll
    for (int m = 0; m < 4; ++m)
#pragma unroll
      for (int n = 0; n < 4; ++n) {
        acc[m][n] = __builtin_amdgcn_mfma_f32_16x16x32_bf16(ah[m], bh[n], acc[m][n], 0, 0, 0);
        acc[m][n] = __builtin_amdgcn_mfma_f32_16x16x32_bf16(ah[m], bl[n], acc[m][n], 0, 0, 0);
        acc[m][n] = __builtin_amdgcn_mfma_f32_16x16x32_bf16(al[m], bh[n], acc[m][n], 0, 0, 0);
      }
  }

  const int g  = lane >> 4;
  const int cl = lane & 15;
  const int tileIdx = bn * 2 + wc;
#pragma unroll
  for (int m = 0; m < 4; ++m) {
#pragma unroll
    for (int j = 0; j < 4; ++j) {
      const int lrow = lbase + wr * 64 + m * 16 + g * 4 + j;
      float v0 = acc[m][0][j], v1 = acc[m][1][j], v2 = acc[m][2][j], v3 = acc[m][3][j];
      float mx = fmaxf(fmaxf(v0, v1), fmaxf(v2, v3));
#pragma unroll
      for (int s2 = 1; s2 < 16; s2 <<= 1) mx = fmaxf(mx, __shfl_xor(mx, s2, 64));
      float p0 = __expf(v0 - mx), p1 = __expf(v1 - mx), p2 = __expf(v2 - mx), p3 = __expf(v3 - mx);
      float sm = p0 + p1 + p2 + p3;
#pragma unroll
      for (int s2 = 1; s2 < 16; s2 <<= 1) sm += __shfl_xor(sm, s2, 64);
      _Float16* ep = expo + (size_t)lrow * KCENT + brow0 + wc * 64;
      ep[ 0 + cl] = (_Float16)p0;
      ep[16 + cl] = (_Float16)p1;
      ep[32 + cl] = (_Float16)p2;
      ep[48 + cl] = (_Float16)p3;
      if (cl == 0) stats[(size_t)lrow * STATS_T + tileIdx] = make_float2(mx, sm);
    }
  }
}

// ---------- kernel 2: combine stats + segmented sum over label-sorted columns ----------
// One row per block. No atomics: columns are label-sorted, classes are contiguous runs.
__launch_bounds__(256)
__global__ void scatter_classes(const _Float16* __restrict__ expo, const float2* __restrict__ stats,
                                const ushort* __restrict__ segstart, float* __restrict__ out,
                                int row0) {
  __shared__ __align__(16) _Float16 srow[KCENT];  // 24 KB: this row's exp values
  __shared__ __align__(16) float souts[NCLS];     // 16 KB: output row staging
  __shared__ ushort ss[NCLS + 1];                 // 8.2 KB
  __shared__ float cf[STATS_T];
  __shared__ float red[8];
  const int row = blockIdx.x;
  const int tid = threadIdx.x;
  const int lane = tid & 63, wv = tid >> 6;

  // stage expo row (coalesced 16B) + segment starts
  const uint4* ep8 = (const uint4*)(expo + (size_t)row * KCENT);
  uint4* sr8 = (uint4*)srow;
#pragma unroll
  for (int i = 0; i < 6; ++i) sr8[i * 256 + tid] = ep8[i * 256 + tid];
  for (int i = tid; i <= NCLS; i += 256) ss[i] = segstart[i];

  // combine per-tile stats: m = max(mt), Z = sum(zt * exp(mt - m)); cf[t] = exp(mt - m)/Z
  float mt = -3.4e38f, zt = 0.f;
  if (tid < STATS_T) {
    float2 s0 = stats[(size_t)row * STATS_T + tid];
    mt = s0.x; zt = s0.y;
  }
  float m = mt;
#pragma unroll
  for (int s2 = 1; s2 < 64; s2 <<= 1) m = fmaxf(m, __shfl_xor(m, s2, 64));
  if (lane == 0) red[wv] = m;
  __syncthreads();
  m = fmaxf(fmaxf(red[0], red[1]), fmaxf(red[2], red[3]));
  float e = (tid < STATS_T) ? __expf(mt - m) : 0.f;
  float z = zt * e;
#pragma unroll
  for (int s2 = 1; s2 < 64; s2 <<= 1) z += __shfl_xor(z, s2, 64);
  if (lane == 0) red[4 + wv] = z;
  __syncthreads();
  z = (red[4] + red[5]) + (red[6] + red[7]);
  if (tid < STATS_T) cf[tid] = e / z;
  __syncthreads();

  // segmented sums; class-strided (c = tid + 256j) keeps lanes ~2/bank on srow reads
#pragma unroll
  for (int j = 0; j < 16; ++j) {
    const int c = tid + j * 256;
    const int a = ss[c], b = ss[c + 1];
    float s = 0.f;
    for (int k = a; k < b; ++k) s += (float)srow[k] * cf[k >> 6];
    souts[c] = s;
  }
  __syncthreads();

  float4* orow = (float4*)(out + (size_t)(row0 + row) * NCLS);
  const float4* o4 = (const float4*)souts;
#pragma unroll
  for (int i = 0; i < 4; ++i) orow[i * 256 + tid] = o4[i * 256 + tid];
}

extern "C" void kernel_launch(void* const* d_in, const int* in_sizes, int n_in,
                              void* d_out, int out_size, void* d_ws, size_t ws_size,
                              hipStream_t stream) {
  (void)in_sizes; (void)n_in; (void)out_size;
  const float* X = (const float*)d_in[0];
  const float* C = (const float*)d_in[1];
  const int* labels = (const int*)d_in[2];
  float* out = (float*)d_out;

  char* ws = (char*)d_ws;
  size_t off = 0;
  auto carve = [&](size_t bytes) -> char* {
    char* p = ws + off;
    off += (bytes + 255) & ~(size_t)255;
    return p;
  };
  __bf16* Xh = (__bf16*)carve((size_t)NROWS * DIM * 2);
  __bf16* Xl = (__bf16*)carve((size_t)NROWS * DIM * 2);
  __bf16* Ch = (__bf16*)carve((size_t)KCENT * DIM * 2);
  __bf16* Cl = (__bf16*)carve((size_t)KCENT * DIM * 2);
  int* iperm = (int*)carve((size_t)KCENT * 4);
  ushort* segstart = (ushort*)carve((size_t)(NCLS + 1) * 2);
  const size_t fixed = off;

  const size_t per_row = (size_t)KCENT * 2 + (size_t)STATS_T * 8;
  size_t avail = (ws_size > fixed + 4096) ? (ws_size - fixed - 4096) : 0;
  long Rmax = (long)(avail / per_row);
  Rmax = (Rmax / 128) * 128;
  if (Rmax < 128) Rmax = 128;
  if (Rmax > NROWS) Rmax = NROWS;
  _Float16* expo = (_Float16*)carve((size_t)Rmax * KCENT * 2);
  float2* stats  = (float2*)carve((size_t)Rmax * STATS_T * 8);

  build_perm<<<1, 256, 0, stream>>>(labels, iperm, segstart);
  {
    int n4x = NROWS * DIM / 4;
    split_convert<<<(n4x + 255) / 256, 256, 0, stream>>>((const float4*)X, (ushort4*)Xh, (ushort4*)Xl, n4x);
    split_convert_perm<<<KCENT, 256, 0, stream>>>((const float4*)C, iperm, (ushort4*)Ch, (ushort4*)Cl);
  }

  for (int r0 = 0; r0 < NROWS; r0 += (int)Rmax) {
    int R = (NROWS - r0 < (int)Rmax) ? (NROWS - r0) : (int)Rmax;
    dim3 grid(R / BM, KCENT / BN);
    gemm_softmax<<<grid, 256, 0, stream>>>(Xh, Xl, Ch, Cl, expo, stats, r0);
    scatter_classes<<<R, 256, 0, stream>>>(expo, stats, segstart, out, r0);
  }
}